// Round 10
// baseline (119.190 us; speedup 1.0000x reference)
//
#include <hip/hip_runtime.h>
#include <stdint.h>

#define NROWS 8192
#define KX    2048      // N*M
#define KA    2112      // KX + NF (augmented K)
#define NF    64
#define DD    2016
#define WCOLS 2080      // NF + DD
#define ODIM  1024
#define BN_EPS 1e-5f

#define A1_OT 32
#define A2_DC 8
#define A2_DPC 252
#define A2_OT 16

#define CONV_RPB 4
#define CONV_NB  (NROWS / CONV_RPB)    // 2048
#define RED_NB   (ODIM * NF / 256)     // 256 reduce blocks folded into conv

#define A1A2_A1N 256
#define A1A2_TOT 768

// GEMM geometry
#define BM 256
#define BN 128
#define BK 64
#define NKT (KA / BK)   // 33

using f32x4  = __attribute__((ext_vector_type(4))) float;
using bf16x8 = __attribute__((ext_vector_type(8))) short;

__device__ __forceinline__ short f2bf(float x) {
    uint32_t u = __float_as_uint(x);
    uint32_t r = (u + 0x7FFFu + ((u >> 16) & 1u)) >> 16;   // RNE to bf16
    return (short)r;
}

__device__ __forceinline__ void gload16(const void* g, void* l) {
    __builtin_amdgcn_global_load_lds(
        (const __attribute__((address_space(1))) uint32_t*)g,
        (__attribute__((address_space(3))) uint32_t*)l, 16, 0, 0);
}

#define MFMA_BF16 __builtin_amdgcn_mfma_f32_16x16x32_bf16

// ---------------------------------------------------------------------------
// Kernel 1a: conv (2048 blocks x 4 rows) + a2_reduce (256 blocks) folded in.
// Runs after a1a2_kern on the stream, so partials are complete.
// ---------------------------------------------------------------------------
__global__ __launch_bounds__(256) void conv_kern(const float* __restrict__ X,
                                                 short* __restrict__ Xa,
                                                 const float* __restrict__ partials,
                                                 short* __restrict__ Aw) {
    const int t = threadIdx.x;
    const int b = blockIdx.x;
    if (b < CONV_NB) {
#pragma unroll
        for (int r = 0; r < CONV_RPB; ++r) {
            const int row = b * CONV_RPB + r;
            const float4* xr = reinterpret_cast<const float4*>(X + (size_t)row * KX);
            float4 v0 = xr[t * 2];
            float4 v1 = xr[t * 2 + 1];
            bf16x8 s;
            s[0] = f2bf(v0.x); s[1] = f2bf(v0.y); s[2] = f2bf(v0.z); s[3] = f2bf(v0.w);
            s[4] = f2bf(v1.x); s[5] = f2bf(v1.y); s[6] = f2bf(v1.z); s[7] = f2bf(v1.w);
            short* outr = Xa + (size_t)row * KA;
            reinterpret_cast<bf16x8*>(outr)[t] = s;
            float sq = v0.x*v0.x + v0.y*v0.y + v0.z*v0.z + v0.w*v0.w
                     + v1.x*v1.x + v1.y*v1.y + v1.z*v1.z + v1.w*v1.w;
            sq += __shfl_xor(sq, 1);
            sq += __shfl_xor(sq, 2);
            if ((t & 3) == 0) outr[KX + (t >> 2)] = f2bf(sq - 32.0f);  // centered
        }
    } else {
        // a2_reduce: sum A2_DC partials -> bf16 Aw cols [2048,2112)
        const int idx = (b - CONV_NB) * 256 + t;   // o*64+n
        const int o = idx >> 6, n = idx & 63;
        float s = 0.f;
#pragma unroll
        for (int c = 0; c < A2_DC; ++c)
            s += partials[((size_t)c * ODIM + o) * NF + n];
        Aw[(size_t)o * KA + KX + n] = f2bf(s);
    }
}

// ---------------------------------------------------------------------------
// Kernel 1b: a1 + a2 (LDS-staged Wa) — unchanged from round 9.
// ---------------------------------------------------------------------------
__global__ __launch_bounds__(256) void a1a2_kern(short* __restrict__ Aw,
                                                 const float* __restrict__ Wa,
                                                 const float* __restrict__ Wz,
                                                 const float* __restrict__ theta,
                                                 float* __restrict__ partials) {
    const int bid = blockIdx.x;
    const int t = threadIdx.x;
    __shared__ __align__(16) float smem[4096];   // 16 KB

    if (bid < A1A2_A1N) {
        const int k = (bid & 7) * 256 + t;
        const int o0 = (bid >> 3) * A1_OT;
        for (int idx = t; idx < A1_OT * 64; idx += 256)
            smem[idx] = Wa[(size_t)(o0 + (idx >> 6)) * WCOLS + (idx & 63)];
        float wz[64];
#pragma unroll
        for (int d = 0; d < 64; ++d) wz[d] = Wz[(size_t)d * KX + k];
        __syncthreads();
#pragma unroll 2
        for (int j = 0; j < A1_OT; ++j) {
            const float* war = &smem[j * 64];
            float acc = 0.f;
#pragma unroll
            for (int d = 0; d < 64; ++d) acc += war[d] * wz[d];
            Aw[(size_t)(o0 + j) * KA + k] = f2bf(acc);
        }
    } else {
        const int b = bid - A1A2_A1N;
        const int n = t & 63;
        const int g = t >> 6;
        const int chunk = b & 7;
        const int o0 = (b >> 3) * A2_OT;
        const int d0 = chunk * A2_DPC;
        float* waT = smem;                       // [A2_OT][A2_DPC] = 4032 floats
        for (int idx = t; idx < A2_OT * A2_DPC; idx += 256) {
            const int j = idx / A2_DPC, dd = idx - j * A2_DPC;
            waT[idx] = Wa[(size_t)(o0 + j) * WCOLS + NF + d0 + dd];
        }
        __syncthreads();
        float acc[A2_OT];
#pragma unroll
        for (int j = 0; j < A2_OT; ++j) acc[j] = 0.f;
        for (int i = g; i < A2_DPC; i += 4) {
            float th = theta[(size_t)(d0 + i) * NF + n];
            float th2 = th * th;
#pragma unroll
            for (int j = 0; j < A2_OT; ++j)
                acc[j] += waT[j * A2_DPC + i] * th2;
        }
        __syncthreads();                          // waT dead; reuse as red
        float* red = smem;                        // [4][A2_OT][64] = 4096
#pragma unroll
        for (int j = 0; j < A2_OT; ++j) red[(g * A2_OT + j) * 64 + n] = acc[j];
        __syncthreads();
#pragma unroll
        for (int k2 = 0; k2 < A2_OT * 64 / 256; ++k2) {
            const int idx = t + k2 * 256;
            const int ol = idx >> 6, nn = idx & 63;
            float s = red[(0 * A2_OT + ol) * 64 + nn] + red[(1 * A2_OT + ol) * 64 + nn]
                    + red[(2 * A2_OT + ol) * 64 + nn] + red[(3 * A2_OT + ol) * 64 + nn];
            partials[((size_t)chunk * ODIM + o0 + ol) * NF + nn] = s;
        }
    }
}

// ---------------------------------------------------------------------------
// Kernel 3: 8-phase-style GEMM.  BM=256 BN=128 BK=64, 512 thr (8 waves 4Mx2N),
// triple-buffered LDS (144 KB), 2-tile-lookahead counted vmcnt(6) (T3+T4),
// 4 barrier-separated phases/K-tile with setprio MFMA clusters (T5),
// XOR slot swizzle on A and B (T2, both-sides: pre-swizzled global source
// + swizzled LDS read; rows are 128 B so unswizzled would be 16-way).
// Epilogue: fused BN column sum/sumsq (bias cancels under BN).
// ---------------------------------------------------------------------------
__global__ __launch_bounds__(512, 2) void gemm_kern(const short* __restrict__ Xa,
                                                    const short* __restrict__ Aw,
                                                    float* __restrict__ C,
                                                    float* __restrict__ sums) {
    __shared__ __align__(16) short AS[3][BM * BK];   // 3 x 32 KB
    __shared__ __align__(16) short BS[3][BN * BK];   // 3 x 16 KB
    const int tid  = threadIdx.x;
    const int lane = tid & 63;
    const int cl   = lane & 15;
    const int kq   = lane >> 4;       // k-quarter within fragment
    const int wid  = tid >> 6;
    const int wr   = wid >> 1;        // 0..3 (M)
    const int wc   = wid & 1;         // 0..1 (N)
    const int bm = blockIdx.x * BM;
    const int bn = blockIdx.y * BN;

    f32x4 acc[4][4] = {};

    // ---- staging maps (16B chunk c: row = c>>3, slot cp = c&7; LDS linear,
    //      global col-chunk = cp ^ (row&7)  -> inverse of the read swizzle)
    const short* gAs[4]; int ldA[4];
    const short* gBs[2]; int ldB[2];
#pragma unroll
    for (int i = 0; i < 4; ++i) {
        const int c = tid + i * 512;            // 0..2047
        const int row = c >> 3, cp = c & 7;
        gAs[i] = Xa + (size_t)(bm + row) * KA + (cp ^ (row & 7)) * 8;
        ldA[i] = c * 8;                          // shorts
    }
#pragma unroll
    for (int i = 0; i < 2; ++i) {
        const int c = tid + i * 512;            // 0..1023
        const int row = c >> 3, cp = c & 7;
        gBs[i] = Aw + (size_t)(bn + row) * KA + (cp ^ (row & 7)) * 8;
        ldB[i] = c * 8;
    }

    // ---- swizzled LDS read offsets (shorts)
    int offA[4][2], offB[4][2];
#pragma unroll
    for (int m = 0; m < 4; ++m) {
        const int r = wr * 64 + m * 16 + cl;
        offA[m][0] = r * BK + ((kq)     ^ (r & 7)) * 8;
        offA[m][1] = r * BK + ((4 + kq) ^ (r & 7)) * 8;
    }
#pragma unroll
    for (int n = 0; n < 4; ++n) {
        const int r = wc * 64 + n * 16 + cl;
        offB[n][0] = r * BK + ((kq)     ^ (r & 7)) * 8;
        offB[n][1] = r * BK + ((4 + kq) ^ (r & 7)) * 8;
    }

#define STAGE_A_PAIR(buf, kt, j) \
    gload16(gAs[2*(j)]     + (size_t)(kt) * BK, &AS[buf][ldA[2*(j)]]); \
    gload16(gAs[2*(j) + 1] + (size_t)(kt) * BK, &AS[buf][ldA[2*(j) + 1]]);
#define STAGE_B_PAIR(buf, kt) \
    gload16(gBs[0] + (size_t)(kt) * BK, &BS[buf][ldB[0]]); \
    gload16(gBs[1] + (size_t)(kt) * BK, &BS[buf][ldB[1]]);

    // ---- prologue: stage tiles 0 and 1 (12 gloads out), wait tile 0 (oldest 6)
    STAGE_A_PAIR(0, 0, 0) STAGE_A_PAIR(0, 0, 1) STAGE_B_PAIR(0, 0)
    STAGE_A_PAIR(1, 1, 0) STAGE_A_PAIR(1, 1, 1) STAGE_B_PAIR(1, 1)
    asm volatile("s_waitcnt vmcnt(6)" ::: "memory");
    __builtin_amdgcn_s_barrier();

    int cb = 0, sb = 2;
    for (int kt = 0; kt < NKT; ++kt) {
        const bool st = (kt + 2 < NKT);
        const short* As = &AS[cb][0];
        const short* Bs = &BS[cb][0];

        // ---- phase 0 (m=0): read all B frags + a[0]; stage A pair 0 of kt+2
        bf16x8 b00 = *(const bf16x8*)(Bs + offB[0][0]);
        bf16x8 b01 = *(const bf16x8*)(Bs + offB[0][1]);
        bf16x8 b10 = *(const bf16x8*)(Bs + offB[1][0]);
        bf16x8 b11 = *(const bf16x8*)(Bs + offB[1][1]);
        bf16x8 b20 = *(const bf16x8*)(Bs + offB[2][0]);
        bf16x8 b21 = *(const bf16x8*)(Bs + offB[2][1]);
        bf16x8 b30 = *(const bf16x8*)(Bs + offB[3][0]);
        bf16x8 b31 = *(const bf16x8*)(Bs + offB[3][1]);
        {
            bf16x8 a0 = *(const bf16x8*)(As + offA[0][0]);
            bf16x8 a1 = *(const bf16x8*)(As + offA[0][1]);
            if (st) { STAGE_A_PAIR(sb, kt + 2, 0) }
            __builtin_amdgcn_s_barrier();
            asm volatile("s_waitcnt lgkmcnt(0)" ::: "memory");
            __builtin_amdgcn_sched_barrier(0);
            __builtin_amdgcn_s_setprio(1);
            acc[0][0] = MFMA_BF16(a0, b00, acc[0][0], 0, 0, 0);
            acc[0][0] = MFMA_BF16(a1, b01, acc[0][0], 0, 0, 0);
            acc[0][1] = MFMA_BF16(a0, b10, acc[0][1], 0, 0, 0);
            acc[0][1] = MFMA_BF16(a1, b11, acc[0][1], 0, 0, 0);
            acc[0][2] = MFMA_BF16(a0, b20, acc[0][2], 0, 0, 0);
            acc[0][2] = MFMA_BF16(a1, b21, acc[0][2], 0, 0, 0);
            acc[0][3] = MFMA_BF16(a0, b30, acc[0][3], 0, 0, 0);
            acc[0][3] = MFMA_BF16(a1, b31, acc[0][3], 0, 0, 0);
            __builtin_amdgcn_s_setprio(0);
            __builtin_amdgcn_s_barrier();
        }
        // ---- phase 1 (m=1): stage A pair 1 of kt+2
        {
            bf16x8 a0 = *(const bf16x8*)(As + offA[1][0]);
            bf16x8 a1 = *(const bf16x8*)(As + offA[1][1]);
            if (st) { STAGE_A_PAIR(sb, kt + 2, 1) }
            __builtin_amdgcn_s_barrier();
            asm volatile("s_waitcnt lgkmcnt(0)" ::: "memory");
            __builtin_amdgcn_sched_barrier(0);
            __builtin_amdgcn_s_setprio(1);
            acc[1][0] = MFMA_BF16(a0, b00, acc[1][0], 0, 0, 0);
            acc[1][0] = MFMA_BF16(a1, b01, acc[1][0], 0, 0, 0);
            acc[1][1] = MFMA_BF16(a0, b10, acc[1][1], 0, 0, 0);
            acc[1][1] = MFMA_BF16(a1, b11, acc[1][1], 0, 0, 0);
            acc[1][2] = MFMA_BF16(a0, b20, acc[1][2], 0, 0, 0);
            acc[1][2] = MFMA_BF16(a1, b21, acc[1][2], 0, 0, 0);
            acc[1][3] = MFMA_BF16(a0, b30, acc[1][3], 0, 0, 0);
            acc[1][3] = MFMA_BF16(a1, b31, acc[1][3], 0, 0, 0);
            __builtin_amdgcn_s_setprio(0);
            __builtin_amdgcn_s_barrier();
        }
        // ---- phase 2 (m=2): stage B pair of kt+2
        {
            bf16x8 a0 = *(const bf16x8*)(As + offA[2][0]);
            bf16x8 a1 = *(const bf16x8*)(As + offA[2][1]);
            if (st) { STAGE_B_PAIR(sb, kt + 2) }
            __builtin_amdgcn_s_barrier();
            asm volatile("s_waitcnt lgkmcnt(0)" ::: "memory");
            __builtin_amdgcn_sched_barrier(0);
            __builtin_amdgcn_s_setprio(1);
            acc[2][0] = MFMA_BF16(a0, b00, acc[2][0], 0, 0, 0);
            acc[2][0] = MFMA_BF16(a1, b01, acc[2][0], 0, 0, 0);
            acc[2][1] = MFMA_BF16(a0, b10, acc[2][1], 0, 0, 0);
            acc[2][1] = MFMA_BF16(a1, b11, acc[2][1], 0, 0, 0);
            acc[2][2] = MFMA_BF16(a0, b20, acc[2][2], 0, 0, 0);
            acc[2][2] = MFMA_BF16(a1, b21, acc[2][2], 0, 0, 0);
            acc[2][3] = MFMA_BF16(a0, b30, acc[2][3], 0, 0, 0);
            acc[2][3] = MFMA_BF16(a1, b31, acc[2][3], 0, 0, 0);
            __builtin_amdgcn_s_setprio(0);
            __builtin_amdgcn_s_barrier();
        }
        // ---- phase 3 (m=3): no stage; end-of-tile counted wait
        {
            bf16x8 a0 = *(const bf16x8*)(As + offA[3][0]);
            bf16x8 a1 = *(const bf16x8*)(As + offA[3][1]);
            __builtin_amdgcn_s_barrier();
            asm volatile("s_waitcnt lgkmcnt(0)" ::: "memory");
            __builtin_amdgcn_sched_barrier(0);
            __builtin_amdgcn_s_setprio(1);
            acc[3][0] = MFMA_BF16(a0, b00, acc[3][0], 0, 0, 0);
            acc[3][0] = MFMA_BF16(a1, b01, acc[3][0], 0, 0, 0);
            acc[3][1] = MFMA_BF16(a0, b10, acc[3][1], 0, 0, 0);
            acc[3][1] = MFMA_BF16(a1, b11, acc[3][1], 0, 0, 0);
            acc[3][2] = MFMA_BF16(a0, b20, acc[3][2], 0, 0, 0);
            acc[3][2] = MFMA_BF16(a1, b21, acc[3][2], 0, 0, 0);
            acc[3][3] = MFMA_BF16(a0, b30, acc[3][3], 0, 0, 0);
            acc[3][3] = MFMA_BF16(a1, b31, acc[3][3], 0, 0, 0);
            __builtin_amdgcn_s_setprio(0);
            if (kt < NKT - 1) {
                // oldest remaining after this wait = tile kt+1's 6 loads done;
                // the newest 6 (tile kt+2, if staged) may stay in flight.
                if (st) asm volatile("s_waitcnt vmcnt(6)" ::: "memory");
                else    asm volatile("s_waitcnt vmcnt(0)" ::: "memory");
            }
            __builtin_amdgcn_s_barrier();
        }
        cb = (cb == 2) ? 0 : cb + 1;
        sb = (sb == 2) ? 0 : sb + 1;
    }

    // ---- epilogue: store C + fused BN column sum/sumsq
    // C/D layout col=lane&15, row=(lane>>4)*4+reg (m89/m91 verified).
    const int rlo = kq * 4;
#pragma unroll
    for (int n = 0; n < 4; ++n) {
        const int col = bn + wc * 64 + n * 16 + cl;
        float s = 0.f, q = 0.f;
#pragma unroll
        for (int m = 0; m < 4; ++m) {
            const int rowb = bm + wr * 64 + m * 16 + rlo;
#pragma unroll
            for (int r2 = 0; r2 < 4; ++r2) {
                float v = acc[m][n][r2];
                C[(size_t)(rowb + r2) * ODIM + col] = v;
                s += v; q += v * v;
            }
        }
        s += __shfl_xor(s, 16); s += __shfl_xor(s, 32);
        q += __shfl_xor(q, 16); q += __shfl_xor(q, 32);
        if (lane < 16) {
            atomicAdd(&sums[col], s);
            atomicAdd(&sums[ODIM + col], q);
        }
    }
}

// ---------------------------------------------------------------------------
// Kernel 4: BN apply with inline finalize (2048 blocks, 4 rows/thread).
// ---------------------------------------------------------------------------
__global__ __launch_bounds__(256) void bn_apply(float* __restrict__ C,
                                                const float* __restrict__ sums,
                                                const float* __restrict__ gamma,
                                                const float* __restrict__ beta) {
    const int g = blockIdx.x * 256 + threadIdx.x;
    const int c4 = g & (ODIM / 4 - 1);
    const int row0 = g >> 8;                        // 0..2047
    const float inv = 1.0f / (float)NROWS;
    float4 sc, sh;
    {
        float4 s0 = reinterpret_cast<const float4*>(sums)[c4];
        float4 q0 = reinterpret_cast<const float4*>(sums + ODIM)[c4];
        float4 gm = reinterpret_cast<const float4*>(gamma)[c4];
        float4 bt = reinterpret_cast<const float4*>(beta)[c4];
        float m, v;
        m = s0.x * inv; v = q0.x * inv - m * m; sc.x = gm.x * rsqrtf(v + BN_EPS); sh.x = bt.x - m * sc.x;
        m = s0.y * inv; v = q0.y * inv - m * m; sc.y = gm.y * rsqrtf(v + BN_EPS); sh.y = bt.y - m * sc.y;
        m = s0.z * inv; v = q0.z * inv - m * m; sc.z = gm.z * rsqrtf(v + BN_EPS); sh.z = bt.z - m * sc.z;
        m = s0.w * inv; v = q0.w * inv - m * m; sc.w = gm.w * rsqrtf(v + BN_EPS); sh.w = bt.w - m * sc.w;
    }
#pragma unroll
    for (int r = 0; r < 4; ++r) {
        const size_t i = (size_t)(row0 + r * 2048) * (ODIM / 4) + c4;
        float4 v = reinterpret_cast<const float4*>(C)[i];
        v.x = v.x * sc.x + sh.x;
        v.y = v.y * sc.y + sh.y;
        v.z = v.z * sc.z + sh.z;
        v.w = v.w * sc.w + sh.w;
        reinterpret_cast<float4*>(C)[i] = v;
    }
}

// ---------------------------------------------------------------------------
extern "C" void kernel_launch(void* const* d_in, const int* in_sizes, int n_in,
                              void* d_out, int out_size, void* d_ws, size_t ws_size,
                              hipStream_t stream) {
    const float* X     = (const float*)d_in[0];
    const float* Wz    = (const float*)d_in[1];
    const float* theta = (const float*)d_in[2];
    const float* Wa    = (const float*)d_in[3];
    const float* gamma = (const float*)d_in[5];
    const float* beta  = (const float*)d_in[6];
    float* out = (float*)d_out;

    char* ws = (char*)d_ws;
    float* sums = (float*)ws;                                        // 2*1024 f32
    short* Xa = (short*)(ws + 16384);                                // 8192*2112 bf16
    short* Aw = (short*)(ws + 16384 + (size_t)NROWS * KA * 2);       // 1024*2112 bf16
    float* partials = (float*)(ws + 16384 + (size_t)NROWS * KA * 2
                                        + (size_t)ODIM * KA * 2);    // 8*1024*64 f32

    hipMemsetAsync(sums, 0, 2 * ODIM * sizeof(float), stream);
    a1a2_kern<<<A1A2_TOT, 256, 0, stream>>>(Aw, Wa, Wz, theta, partials);
    conv_kern<<<CONV_NB + RED_NB, 256, 0, stream>>>(X, Xa, partials, Aw);
    gemm_kern<<<dim3(NROWS / BM, ODIM / BN), 512, 0, stream>>>(Xa, Aw, out, sums);
    bn_apply<<<NROWS / 4 * ODIM / 4 / 256, 256, 0, stream>>>(out, sums, gamma, beta);
}

// Round 11
// 114.823 us; speedup vs baseline: 1.0380x; 1.0380x over previous
//
#include <hip/hip_runtime.h>
#include <stdint.h>

#define NROWS 8192
#define KX    2048      // N*M
#define KA    2112      // KX + NF (augmented K)
#define NF    64
#define DD    2016
#define WCOLS 2080      // NF + DD
#define ODIM  1024
#define BN_EPS 1e-5f

#define A1_OT 32
#define A2_DC 8
#define A2_DPC 252
#define A2_OT 16

#define CONV_RPB 4
#define CONV_NB  (NROWS / CONV_RPB)    // 2048
#define RED_NB   (ODIM * NF / 256)     // 256 reduce blocks folded into conv

#define A1A2_A1N 256
#define A1A2_TOT 768

#define NT (KA / 32)    // 66 K-tiles, divisible by 3

using f32x4  = __attribute__((ext_vector_type(4))) float;
using bf16x8 = __attribute__((ext_vector_type(8))) short;

__device__ __forceinline__ short f2bf(float x) {
    uint32_t u = __float_as_uint(x);
    uint32_t r = (u + 0x7FFFu + ((u >> 16) & 1u)) >> 16;   // RNE to bf16
    return (short)r;
}

__device__ __forceinline__ void gload16(const void* g, void* l) {
    __builtin_amdgcn_global_load_lds(
        (const __attribute__((address_space(1))) uint32_t*)g,
        (__attribute__((address_space(3))) uint32_t*)l, 16, 0, 0);
}

#define MFMA_BF16 __builtin_amdgcn_mfma_f32_16x16x32_bf16

// ---------------------------------------------------------------------------
// Kernel 1a: conv (2048 blocks x 4 rows) + a2_reduce (256 blocks) folded in.
// Runs after a1a2_kern on the stream, so partials are complete.
// ---------------------------------------------------------------------------
__global__ __launch_bounds__(256) void conv_kern(const float* __restrict__ X,
                                                 short* __restrict__ Xa,
                                                 const float* __restrict__ partials,
                                                 short* __restrict__ Aw) {
    const int t = threadIdx.x;
    const int b = blockIdx.x;
    if (b < CONV_NB) {
#pragma unroll
        for (int r = 0; r < CONV_RPB; ++r) {
            const int row = b * CONV_RPB + r;
            const float4* xr = reinterpret_cast<const float4*>(X + (size_t)row * KX);
            float4 v0 = xr[t * 2];
            float4 v1 = xr[t * 2 + 1];
            bf16x8 s;
            s[0] = f2bf(v0.x); s[1] = f2bf(v0.y); s[2] = f2bf(v0.z); s[3] = f2bf(v0.w);
            s[4] = f2bf(v1.x); s[5] = f2bf(v1.y); s[6] = f2bf(v1.z); s[7] = f2bf(v1.w);
            short* outr = Xa + (size_t)row * KA;
            reinterpret_cast<bf16x8*>(outr)[t] = s;
            float sq = v0.x*v0.x + v0.y*v0.y + v0.z*v0.z + v0.w*v0.w
                     + v1.x*v1.x + v1.y*v1.y + v1.z*v1.z + v1.w*v1.w;
            sq += __shfl_xor(sq, 1);
            sq += __shfl_xor(sq, 2);
            if ((t & 3) == 0) outr[KX + (t >> 2)] = f2bf(sq - 32.0f);  // centered
        }
    } else {
        // a2_reduce: sum A2_DC partials -> bf16 Aw cols [2048,2112)
        const int idx = (b - CONV_NB) * 256 + t;   // o*64+n
        const int o = idx >> 6, n = idx & 63;
        float s = 0.f;
#pragma unroll
        for (int c = 0; c < A2_DC; ++c)
            s += partials[((size_t)c * ODIM + o) * NF + n];
        Aw[(size_t)o * KA + KX + n] = f2bf(s);
    }
}

// ---------------------------------------------------------------------------
// Kernel 1b: a1 + a2 (LDS-staged Wa) — unchanged.
// ---------------------------------------------------------------------------
__global__ __launch_bounds__(256) void a1a2_kern(short* __restrict__ Aw,
                                                 const float* __restrict__ Wa,
                                                 const float* __restrict__ Wz,
                                                 const float* __restrict__ theta,
                                                 float* __restrict__ partials) {
    const int bid = blockIdx.x;
    const int t = threadIdx.x;
    __shared__ __align__(16) float smem[4096];   // 16 KB

    if (bid < A1A2_A1N) {
        const int k = (bid & 7) * 256 + t;
        const int o0 = (bid >> 3) * A1_OT;
        for (int idx = t; idx < A1_OT * 64; idx += 256)
            smem[idx] = Wa[(size_t)(o0 + (idx >> 6)) * WCOLS + (idx & 63)];
        float wz[64];
#pragma unroll
        for (int d = 0; d < 64; ++d) wz[d] = Wz[(size_t)d * KX + k];
        __syncthreads();
#pragma unroll 2
        for (int j = 0; j < A1_OT; ++j) {
            const float* war = &smem[j * 64];
            float acc = 0.f;
#pragma unroll
            for (int d = 0; d < 64; ++d) acc += war[d] * wz[d];
            Aw[(size_t)(o0 + j) * KA + k] = f2bf(acc);
        }
    } else {
        const int b = bid - A1A2_A1N;
        const int n = t & 63;
        const int g = t >> 6;
        const int chunk = b & 7;
        const int o0 = (b >> 3) * A2_OT;
        const int d0 = chunk * A2_DPC;
        float* waT = smem;                       // [A2_OT][A2_DPC] = 4032 floats
        for (int idx = t; idx < A2_OT * A2_DPC; idx += 256) {
            const int j = idx / A2_DPC, dd = idx - j * A2_DPC;
            waT[idx] = Wa[(size_t)(o0 + j) * WCOLS + NF + d0 + dd];
        }
        __syncthreads();
        float acc[A2_OT];
#pragma unroll
        for (int j = 0; j < A2_OT; ++j) acc[j] = 0.f;
        for (int i = g; i < A2_DPC; i += 4) {
            float th = theta[(size_t)(d0 + i) * NF + n];
            float th2 = th * th;
#pragma unroll
            for (int j = 0; j < A2_OT; ++j)
                acc[j] += waT[j * A2_DPC + i] * th2;
        }
        __syncthreads();                          // waT dead; reuse as red
        float* red = smem;                        // [4][A2_OT][64] = 4096
#pragma unroll
        for (int j = 0; j < A2_OT; ++j) red[(g * A2_OT + j) * 64 + n] = acc[j];
        __syncthreads();
#pragma unroll
        for (int k2 = 0; k2 < A2_OT * 64 / 256; ++k2) {
            const int idx = t + k2 * 256;
            const int ol = idx >> 6, nn = idx & 63;
            float s = red[(0 * A2_OT + ol) * 64 + nn] + red[(1 * A2_OT + ol) * 64 + nn]
                    + red[(2 * A2_OT + ol) * 64 + nn] + red[(3 * A2_OT + ol) * 64 + nn];
            partials[((size_t)chunk * ODIM + o0 + ol) * NF + nn] = s;
        }
    }
}

// ---------------------------------------------------------------------------
// Kernel 3: GEMM — 128x128 tile, BK=32, 4 waves (proven 678-TF structure)
// upgraded to a 3-buffer, 2-tile-lookahead pipeline:
//   per K-tile: {stage kt+2 (4 gloads)} {8 ds_read_b128} {16 MFMA}
//               {s_waitcnt vmcnt(4) — kt+1 ready, kt+2 stays in flight}
//               {raw s_barrier — no compiler vmcnt(0) drain}
// Static buffer indices via 3-step unrolled loop (rule #20; NT=66 = 3*22).
// Epilogue: fused BN column sum/sumsq (bias cancels under BN).
// ---------------------------------------------------------------------------
__global__ __launch_bounds__(256) void gemm_kern(const short* __restrict__ Xa,
                                                 const short* __restrict__ Aw,
                                                 float* __restrict__ C,
                                                 float* __restrict__ sums) {
    __shared__ __align__(16) short As[3][128 * 32];
    __shared__ __align__(16) short Bs[3][128 * 32];
    const int tid  = threadIdx.x;
    const int lane = tid & 63;
    const int wid  = tid >> 6;
    const int wr = wid >> 1, wc = wid & 1;
    const int bm = blockIdx.x * 128;
    const int bn = blockIdx.y * 128;

    f32x4 acc[4][4] = {};

    // Staging: chunk c (16B) at LDS pos c holds global slot q = (c&3) ^ ((r>>1)&3)
    const int c0 = tid, c1 = tid + 256;
    const int r0 = c0 >> 2, q0 = (c0 & 3) ^ ((r0 >> 1) & 3);
    const int r1 = c1 >> 2, q1 = (c1 & 3) ^ ((r1 >> 1) & 3);
    const short* gA0 = Xa + (size_t)(bm + r0) * KA + q0 * 8;
    const short* gA1 = Xa + (size_t)(bm + r1) * KA + q1 * 8;
    const short* gB0 = Aw + (size_t)(bn + r0) * KA + q0 * 8;
    const short* gB1 = Aw + (size_t)(bn + r1) * KA + q1 * 8;
    const int l0 = c0 * 8, l1 = c1 * 8;

    // Swizzled LDS read offsets
    const int lq = lane >> 4;
    int offA[4], offB[4];
#pragma unroll
    for (int m = 0; m < 4; ++m) {
        int ra = wr * 64 + m * 16 + (lane & 15);
        offA[m] = ra * 32 + (lq ^ ((ra >> 1) & 3)) * 8;
        int rb = wc * 64 + m * 16 + (lane & 15);
        offB[m] = rb * 32 + (lq ^ ((rb >> 1) & 3)) * 8;
    }

#define STAGE(buf, kt) do {                         \
        const int ko_ = (kt) * 32;                  \
        gload16(gA0 + ko_, &As[buf][l0]);           \
        gload16(gA1 + ko_, &As[buf][l1]);           \
        gload16(gB0 + ko_, &Bs[buf][l0]);           \
        gload16(gB1 + ko_, &Bs[buf][l1]);           \
    } while (0)

    // TILE(cbuf, sbuf, kt): compute tile kt from buffer cbuf, prefetch kt+2
    // into sbuf.  One raw barrier per tile; counted vmcnt keeps kt+2's loads
    // in flight across it (the whole point — never drain to 0).
#define TILE(cbuf, sbuf, kt) do {                                          \
        if ((kt) + 2 < NT) STAGE(sbuf, (kt) + 2);                          \
        bf16x8 a_[4], b_[4];                                               \
        _Pragma("unroll")                                                  \
        for (int m = 0; m < 4; ++m)                                        \
            a_[m] = *reinterpret_cast<const bf16x8*>(&As[cbuf][offA[m]]);  \
        _Pragma("unroll")                                                  \
        for (int n = 0; n < 4; ++n)                                        \
            b_[n] = *reinterpret_cast<const bf16x8*>(&Bs[cbuf][offB[n]]);  \
        asm volatile("s_waitcnt lgkmcnt(0)" ::: "memory");                 \
        __builtin_amdgcn_sched_barrier(0);                                 \
        _Pragma("unroll")                                                  \
        for (int m = 0; m < 4; ++m)                                        \
            _Pragma("unroll")                                              \
            for (int n = 0; n < 4; ++n)                                    \
                acc[m][n] = MFMA_BF16(a_[m], b_[n], acc[m][n], 0, 0, 0);   \
        if ((kt) + 2 < NT)                                                 \
            asm volatile("s_waitcnt vmcnt(4)" ::: "memory");               \
        else if ((kt) + 1 < NT)                                            \
            asm volatile("s_waitcnt vmcnt(0)" ::: "memory");               \
        __builtin_amdgcn_s_barrier();                                      \
    } while (0)

    // prologue: stage tiles 0,1; wait for tile 0 (oldest 4 of 8)
    STAGE(0, 0);
    STAGE(1, 1);
    asm volatile("s_waitcnt vmcnt(4)" ::: "memory");
    __builtin_amdgcn_s_barrier();

    for (int kt = 0; kt < NT; kt += 3) {
        TILE(0, 2, kt);
        TILE(1, 0, kt + 1);
        TILE(2, 1, kt + 2);
    }
#undef TILE
#undef STAGE

    // Epilogue: store C (pre-BN) + fused column sum/sumsq partials.
    // C/D layout col=lane&15, row=(lane>>4)*4+reg (m89/m91 verified).
    const int rlo = (lane >> 4) * 4;
    const int cl  = lane & 15;
#pragma unroll
    for (int n = 0; n < 4; ++n) {
        const int col = bn + wc * 64 + n * 16 + cl;
        float s = 0.f, q = 0.f;
#pragma unroll
        for (int m = 0; m < 4; ++m) {
            const int rowb = bm + wr * 64 + m * 16 + rlo;
#pragma unroll
            for (int r2 = 0; r2 < 4; ++r2) {
                float v = acc[m][n][r2];
                C[(size_t)(rowb + r2) * ODIM + col] = v;
                s += v; q += v * v;
            }
        }
        s += __shfl_xor(s, 16); s += __shfl_xor(s, 32);
        q += __shfl_xor(q, 16); q += __shfl_xor(q, 32);
        if (lane < 16) {
            atomicAdd(&sums[col], s);
            atomicAdd(&sums[ODIM + col], q);
        }
    }
}

// ---------------------------------------------------------------------------
// Kernel 4: BN apply with inline finalize (2048 blocks, 4 rows/thread).
// ---------------------------------------------------------------------------
__global__ __launch_bounds__(256) void bn_apply(float* __restrict__ C,
                                                const float* __restrict__ sums,
                                                const float* __restrict__ gamma,
                                                const float* __restrict__ beta) {
    const int g = blockIdx.x * 256 + threadIdx.x;
    const int c4 = g & (ODIM / 4 - 1);
    const int row0 = g >> 8;                        // 0..2047
    const float inv = 1.0f / (float)NROWS;
    float4 sc, sh;
    {
        float4 s0 = reinterpret_cast<const float4*>(sums)[c4];
        float4 q0 = reinterpret_cast<const float4*>(sums + ODIM)[c4];
        float4 gm = reinterpret_cast<const float4*>(gamma)[c4];
        float4 bt = reinterpret_cast<const float4*>(beta)[c4];
        float m, v;
        m = s0.x * inv; v = q0.x * inv - m * m; sc.x = gm.x * rsqrtf(v + BN_EPS); sh.x = bt.x - m * sc.x;
        m = s0.y * inv; v = q0.y * inv - m * m; sc.y = gm.y * rsqrtf(v + BN_EPS); sh.y = bt.y - m * sc.y;
        m = s0.z * inv; v = q0.z * inv - m * m; sc.z = gm.z * rsqrtf(v + BN_EPS); sh.z = bt.z - m * sc.z;
        m = s0.w * inv; v = q0.w * inv - m * m; sc.w = gm.w * rsqrtf(v + BN_EPS); sh.w = bt.w - m * sc.w;
    }
#pragma unroll
    for (int r = 0; r < 4; ++r) {
        const size_t i = (size_t)(row0 + r * 2048) * (ODIM / 4) + c4;
        float4 v = reinterpret_cast<const float4*>(C)[i];
        v.x = v.x * sc.x + sh.x;
        v.y = v.y * sc.y + sh.y;
        v.z = v.z * sc.z + sh.z;
        v.w = v.w * sc.w + sh.w;
        reinterpret_cast<float4*>(C)[i] = v;
    }
}

// ---------------------------------------------------------------------------
extern "C" void kernel_launch(void* const* d_in, const int* in_sizes, int n_in,
                              void* d_out, int out_size, void* d_ws, size_t ws_size,
                              hipStream_t stream) {
    const float* X     = (const float*)d_in[0];
    const float* Wz    = (const float*)d_in[1];
    const float* theta = (const float*)d_in[2];
    const float* Wa    = (const float*)d_in[3];
    const float* gamma = (const float*)d_in[5];
    const float* beta  = (const float*)d_in[6];
    float* out = (float*)d_out;

    char* ws = (char*)d_ws;
    float* sums = (float*)ws;                                        // 2*1024 f32
    short* Xa = (short*)(ws + 16384);                                // 8192*2112 bf16
    short* Aw = (short*)(ws + 16384 + (size_t)NROWS * KA * 2);       // 1024*2112 bf16
    float* partials = (float*)(ws + 16384 + (size_t)NROWS * KA * 2
                                        + (size_t)ODIM * KA * 2);    // 8*1024*64 f32

    hipMemsetAsync(sums, 0, 2 * ODIM * sizeof(float), stream);
    a1a2_kern<<<A1A2_TOT, 256, 0, stream>>>(Aw, Wa, Wz, theta, partials);
    conv_kern<<<CONV_NB + RED_NB, 256, 0, stream>>>(X, Xa, partials, Aw);
    gemm_kern<<<dim3(NROWS / 128, ODIM / 128), 256, 0, stream>>>(Xa, Aw, out, sums);
    bn_apply<<<NROWS / 4 * ODIM / 4 / 256, 256, 0, stream>>>(out, sums, gamma, beta);
}